// Round 4
// baseline (356.110 us; speedup 1.0000x reference)
//
#include <hip/hip_runtime.h>

typedef _Float16 f16;
typedef __attribute__((ext_vector_type(4))) _Float16 f16x4;
typedef __attribute__((ext_vector_type(8))) _Float16 f16x8;
typedef __attribute__((ext_vector_type(4))) float f32x4;

constexpr int BATCH  = 4096;
constexpr int SEQ    = 512;
constexpr int HID    = 64;
constexpr int VOCAB  = 50257;
constexpr float LOG2E2 = 2.8853900817779268f;   // 2*log2(e), folded into embP/Whh

// Only the gfx950-verified K32 f16 shape is used.
#define MFMA_K32(a, b, c) __builtin_amdgcn_mfma_f32_16x16x32_f16(a, b, c, 0, 0, 0)

// ---- Prep: embP[v][f] = LOG2E2*(emb[v].Wih[f] + bih[f] + bhh[f]) in f32,
// rounded once to f16 (input projection folded into the gather table);
// Whh -> f16 pre-scaled; zero BN acc. Within a wave all 64 lanes share one
// v (emb row loads broadcast); Wih is 16 KB -> L1-resident.
__global__ __launch_bounds__(256) void prep_kernel(
    const float* __restrict__ emb, const float* __restrict__ Wih,
    const float* __restrict__ Whh, const float* __restrict__ bih,
    const float* __restrict__ bhh,
    f16* __restrict__ embP, f16* __restrict__ whh_f, float* __restrict__ bn_acc)
{
  const int gid = blockIdx.x * 256 + threadIdx.x;
  if (gid < VOCAB * 64) {
    const int v = gid >> 6, f = gid & 63;
    const float4* er = (const float4*)(emb + v * 64);
    const float4* wr = (const float4*)(Wih + f * 64);
    float acc = bih[f] + bhh[f];
    #pragma unroll
    for (int k = 0; k < 16; ++k) {
      float4 e = er[k], wv = wr[k];
      acc = fmaf(e.x, wv.x, acc); acc = fmaf(e.y, wv.y, acc);
      acc = fmaf(e.z, wv.z, acc); acc = fmaf(e.w, wv.w, acc);
    }
    embP[gid] = (f16)(acc * LOG2E2);
  } else if (gid < VOCAB * 64 + 4096) {
    const int i = gid - VOCAB * 64;
    whh_f[i] = (f16)(Whh[i] * LOG2E2);
  } else if (gid < VOCAB * 64 + 4096 + 128) {
    bn_acc[gid - (VOCAB * 64 + 4096)] = 0.f;   // ws is poisoned 0xAA every call
  }
}

// ---- Kernel 1: fused gather + tanh-RNN scan. TWO waves per 16-row chain
// (256 blocks x 128 thr). Swapped product D = W*h^T, permuted-K K32 (HW-
// validated round 3): B-chunk c's fragment == concat of D-tile quads
// {2c, 2c+1}. Wave w owns f-tiles {2w, 2w+1}, so its own D output IS
// chunk w's B-fragment for the next step; chunk w^1 is exchanged with the
// peer wave via one 16B LDS slot (double-buffered) + an lgkmcnt-only
// barrier -- the 4-deep embP register prefetch stays in flight across it.
// Per wave per step: 4 MFMA + 8 tanh (16 trans) + 1 ds_write + 1 ds_read.
// Input projection is pre-folded into embP, so the gather directly
// initializes the accumulator.
__global__ __launch_bounds__(128, 1) void rnn_scan_kernel(
    const int* __restrict__ xx, const f16* __restrict__ embP,
    const f16* __restrict__ whh,
    float* __restrict__ hT /* [HID][BATCH] */, float* __restrict__ bn_acc)
{
  __shared__ int4 xslot[2][2][64];   // [parity][wave][lane], 16B fragments, 4 KB
  const int tid = threadIdx.x;
  const int w = tid >> 6;          // wave id: owns f-tiles {2w, 2w+1}
  const int L = tid & 63;
  const int n = L & 15;            // batch col within tile / W row within tile
  const int q = L >> 4;            // k-group
  const int R0 = blockIdx.x << 4;  // first batch row of this chain

  // A-fragments: local tile j (global f = 2w+j), K-chunk c. Permuted K:
  // elems 0..3 = Whh[16f+n][32c+4q+e], elems 4..7 = Whh[16f+n][32c+16+4q+e].
  f16x8 Wp[2][2];
  #pragma unroll
  for (int j = 0; j < 2; ++j) {
    const f16* wr = whh + (16 * (2 * w + j) + n) * 64;
    #pragma unroll
    for (int c = 0; c < 2; ++c) {
      f16x4 lo = *(const f16x4*)(wr + 32 * c + 4 * q);
      f16x4 hi = *(const f16x4*)(wr + 32 * c + 16 + 4 * q);
      Wp[j][c] = __builtin_shufflevector(lo, hi, 0, 1, 2, 3, 4, 5, 6, 7);
    }
  }

  // Own h fragment (B-chunk w) = 0; publish h0 into parity-0 slot.
  f16x8 hOwn = {0, 0, 0, 0, 0, 0, 0, 0};
  xslot[0][w][L] = int4{0, 0, 0, 0};

  // idx stream: int4 = 4 steps; K1 holds steps 4(t+1)..4(t+1)+3.
  const int4* x4 = (const int4*)(xx + (R0 + n) * SEQ);
  int4 K1 = x4[1];

  // embP gather: lane (q,n) of wave w needs feats {32w+4q..+3, 32w+16+4q..+3}
  // of its token's projected row. 4-slot rotating register prefetch.
  const f16* ebase = embP + 32 * w + 4 * q;
  f16x4 ep0[4], ep1[4];
  {
    int4 K0 = x4[0];
    const int id0[4] = {K0.x, K0.y, K0.z, K0.w};
    #pragma unroll
    for (int u = 0; u < 4; ++u) {
      const f16* eb = ebase + (long)id0[u] * 64;
      ep0[u] = *(const f16x4*)(eb);
      ep1[u] = *(const f16x4*)(eb + 16);
    }
  }

  // LDS-only barrier (h0 publish visible); vmcnt untouched -> prefetch lives.
  asm volatile("s_waitcnt lgkmcnt(0)\n\ts_barrier" ::: "memory");

  for (int t = 0; t < SEQ / 4; ++t) {
    int4 K2 = x4[(t + 2 < SEQ / 4) ? t + 2 : SEQ / 4 - 1];  // clamped; dup loads harmless
    const int nid[4] = {K1.x, K1.y, K1.z, K1.w};            // idx for steps 4t+4+u
    const bool lastt = (t == SEQ / 4 - 1);

    #pragma unroll
    for (int u = 0; u < 4; ++u) {
      const int p = u & 1;                       // step parity
      // Peer wave's chunk for THIS step (read issued early; first use is
      // after own-chunk MFMAs + refill -> ds latency mostly hidden).
      int4 oraw = xslot[p][w ^ 1][L];

      // D init = gathered input projection (bias & scale pre-folded).
      f32x4 D0, D1;
      #pragma unroll
      for (int r = 0; r < 4; ++r) {
        D0[r] = (float)ep0[u][r];
        D1[r] = (float)ep1[u][r];
      }

      // Own-chunk MFMAs (chunk w): B-fragment is register-resident hOwn.
      D0 = MFMA_K32(Wp[0][w], hOwn, D0);
      D1 = MFMA_K32(Wp[1][w], hOwn, D1);

      // Refill slot u with step s+4 (stays in flight across 4 barriers).
      {
        const f16* eb = ebase + (long)nid[u] * 64;
        ep0[u] = *(const f16x4*)(eb);
        ep1[u] = *(const f16x4*)(eb + 16);
      }

      // Peer-chunk MFMAs.
      union { int4 i; f16x8 h; } cv; cv.i = oraw;
      D0 = MFMA_K32(Wp[0][w ^ 1], cv.h, D0);
      D1 = MFMA_K32(Wp[1][w ^ 1], cv.h, D1);

      // tanh(v) = 1 - 2/(1 + 2^(2log2e*v)); exact saturation at +-1.
      float th[2][4];
      #pragma unroll
      for (int r = 0; r < 4; ++r) {
        float ea = __builtin_amdgcn_exp2f(D0[r]);
        float eb2 = __builtin_amdgcn_exp2f(D1[r]);
        th[0][r] = fmaf(-2.0f, __builtin_amdgcn_rcpf(ea + 1.0f), 1.0f);
        th[1][r] = fmaf(-2.0f, __builtin_amdgcn_rcpf(eb2 + 1.0f), 1.0f);
        hOwn[r]     = (f16)th[0][r];
        hOwn[4 + r] = (f16)th[1][r];
      }

      if (lastt && u == 3) {   // epilogue: h_n out + BN partial sums
        #pragma unroll
        for (int j = 0; j < 2; ++j) {
          #pragma unroll
          for (int r = 0; r < 4; ++r) {
            float v = th[j][r];
            const int feat = 16 * (2 * w + j) + 4 * q + r;
            hT[feat * BATCH + R0 + n] = v;     // coalesced over n
            float s1 = v, s2 = v * v;
            s1 += __shfl_xor(s1, 1, 64);  s2 += __shfl_xor(s2, 1, 64);
            s1 += __shfl_xor(s1, 2, 64);  s2 += __shfl_xor(s2, 2, 64);
            s1 += __shfl_xor(s1, 4, 64);  s2 += __shfl_xor(s2, 4, 64);
            s1 += __shfl_xor(s1, 8, 64);  s2 += __shfl_xor(s2, 8, 64);
            if (n == 0) {
              atomicAdd(bn_acc + feat, s1);
              atomicAdd(bn_acc + 64 + feat, s2);
            }
          }
        }
      }

      // Publish own new h for step s+1 into the other parity slot.
      union { f16x8 h; int4 i; } cw; cw.h = hOwn;
      xslot[p ^ 1][w][L] = cw.i;

      // LDS-only barrier: ds ops drained (lgkmcnt), vmcnt untouched.
      asm volatile("s_waitcnt lgkmcnt(0)\n\ts_barrier" ::: "memory");
    }
    K1 = K2;
  }
}

// ---- Kernel 2: BN fold (from accumulated sums) + logits GEMV. fp32 out.
__global__ __launch_bounds__(256) void head_kernel(
    const float* __restrict__ hT, const float* __restrict__ bn_acc,
    const float* __restrict__ gamma, const float* __restrict__ beta,
    const float* __restrict__ Wfc, const float* __restrict__ bfc,
    float* __restrict__ out)
{
  __shared__ float sc[64], sh[64];
  const int tid = threadIdx.x;
  if (tid < 64) {
    float mean = bn_acc[tid] * (1.0f / BATCH);
    float var  = bn_acc[64 + tid] * (1.0f / BATCH) - mean * mean;  // biased
    float inv  = rsqrtf(var + 1e-5f);
    float s    = gamma[tid] * inv;
    sc[tid] = s;
    sh[tid] = beta[tid] - mean * s;
  }
  __syncthreads();
  const int b = blockIdx.x * 256 + tid;
  float acc[5];
  #pragma unroll
  for (int c = 0; c < 5; ++c) acc[c] = bfc[c];
  for (int j = 0; j < HID; ++j) {
    float hv  = hT[j * BATCH + b];                 // coalesced across lanes
    float hat = fmaf(hv, sc[j], sh[j]);
    #pragma unroll
    for (int c = 0; c < 5; ++c) acc[c] = fmaf(hat, Wfc[c * 64 + j], acc[c]);
  }
  #pragma unroll
  for (int c = 0; c < 5; ++c) out[b * 5 + c] = acc[c];
}

extern "C" void kernel_launch(void* const* d_in, const int* in_sizes, int n_in,
                              void* d_out, int out_size, void* d_ws, size_t ws_size,
                              hipStream_t stream)
{
  const int*   x     = (const int*)d_in[0];
  const float* emb   = (const float*)d_in[1];
  const float* W_ih  = (const float*)d_in[2];
  const float* W_hh  = (const float*)d_in[3];
  const float* b_ih  = (const float*)d_in[4];
  const float* b_hh  = (const float*)d_in[5];
  const float* gamma = (const float*)d_in[6];
  const float* beta  = (const float*)d_in[7];
  const float* W_fc  = (const float*)d_in[8];
  const float* b_fc  = (const float*)d_in[9];

  char* ws = (char*)d_ws;
  float* hT     = (float*)ws;                 // [64][4096] fp32, 1 MB
  float* bn_acc = (float*)(ws + 1048576);     // [2][64] fp32 atomics
  f16*   embP   = (f16*)(ws + 1049088);       // [50257][64] f16 projected, 6.43 MB
  f16*   whh_f  = (f16*)(ws + 7481984);       // [64][64] f16 (pre-scaled)

  const int prep_items = VOCAB * 64 + 4096 + 128;
  prep_kernel<<<dim3((prep_items + 255) / 256), dim3(256), 0, stream>>>(
      emb, W_ih, W_hh, b_ih, b_hh, embP, whh_f, bn_acc);
  rnn_scan_kernel<<<dim3(BATCH / 16), dim3(128), 0, stream>>>(
      x, embP, whh_f, hT, bn_acc);
  head_kernel<<<dim3(BATCH / 256), dim3(256), 0, stream>>>(
      hT, bn_acc, gamma, beta, W_fc, b_fc, (float*)d_out);
}

// Round 5
// 297.320 us; speedup vs baseline: 1.1977x; 1.1977x over previous
//
#include <hip/hip_runtime.h>

typedef _Float16 f16;
typedef __attribute__((ext_vector_type(4))) _Float16 f16x4;
typedef __attribute__((ext_vector_type(8))) _Float16 f16x8;
typedef __attribute__((ext_vector_type(4))) float f32x4;

constexpr int BATCH  = 4096;
constexpr int SEQ    = 512;
constexpr int HID    = 64;
constexpr int VOCAB  = 50257;
constexpr int NBLK_GEMM = 786;   // ceil(ceil(VOCAB/16)/4) GEMM blocks in prep
constexpr float LOG2E2 = 2.8853900817779268f;   // 2*log2(e), folded into embP/Whh

// Only the gfx950-verified K32 f16 shape is used.
#define MFMA_K32(a, b, c) __builtin_amdgcn_mfma_f32_16x16x32_f16(a, b, c, 0, 0, 0)

// ---- Prep: embP[v][f] = f16( LOG2E2*(bih+bhh)[f] + (f16)emb[v] . (f16)(LOG2E2*Wih[f]) )
// computed as an MFMA GEMM (swapped product, r3-proven fragment layouts):
// one wave per 16 vocab rows, A = scaled Wih (4 f-tiles), B = emb^T.
// This replaces round 4's scalar-dot prep (185 us: stride-256 lane reads
// serialized on L1). Numerics: f16 inputs (as r3's in-scan IP) + one f16
// output rounding (as r4's table) -- both passed at absmax 0.0078125.
// Tail block (blockIdx == NBLK_GEMM): Whh -> f16 pre-scaled; zero BN acc.
__global__ __launch_bounds__(256) void prep_kernel(
    const float* __restrict__ emb, const float* __restrict__ Wih,
    const float* __restrict__ Whh, const float* __restrict__ bih,
    const float* __restrict__ bhh,
    f16* __restrict__ embP, f16* __restrict__ whh_f, float* __restrict__ bn_acc)
{
  const int bid = blockIdx.x;
  const int tid = threadIdx.x;
  if (bid == NBLK_GEMM) {        // tail: weight conversion + BN acc zero
    #pragma unroll
    for (int k = 0; k < 16; ++k) {
      const int i = tid * 16 + k;          // 256*16 = 4096 = HID*HID
      whh_f[i] = (f16)(Whh[i] * LOG2E2);
    }
    if (tid < 128) bn_acc[tid] = 0.f;      // ws is poisoned 0xAA every call
    return;
  }
  const int w = tid >> 6;          // wave -> one 16-row group
  const int L = tid & 63;
  const int n = L & 15;
  const int q = L >> 4;
  const int R0 = (bid * 4 + w) * 16;
  int v = R0 + n;
  const bool ok = v < VOCAB;
  if (!ok) v = VOCAB - 1;          // clamp loads; store guarded

  // A-frags: Wi[f][half] elem e = (f16)(LOG2E2 * Wih[16f+n][32*half+8q+e])
  f16x8 Wi[4][2];
  f32x4 bias[4];
  #pragma unroll
  for (int f = 0; f < 4; ++f) {
    const float* wr = Wih + (16 * f + n) * 64;
    #pragma unroll
    for (int h = 0; h < 2; ++h) {
      float4 w0 = *(const float4*)(wr + 32 * h + 8 * q);
      float4 w1 = *(const float4*)(wr + 32 * h + 8 * q + 4);
      Wi[f][h] = (f16x8){
        (f16)(w0.x * LOG2E2), (f16)(w0.y * LOG2E2),
        (f16)(w0.z * LOG2E2), (f16)(w0.w * LOG2E2),
        (f16)(w1.x * LOG2E2), (f16)(w1.y * LOG2E2),
        (f16)(w1.z * LOG2E2), (f16)(w1.w * LOG2E2)};
    }
    float4 bi = *(const float4*)(bih + 16 * f + 4 * q);
    float4 bh = *(const float4*)(bhh + 16 * f + 4 * q);
    bias[f] = (f32x4){(bi.x + bh.x) * LOG2E2, (bi.y + bh.y) * LOG2E2,
                      (bi.z + bh.z) * LOG2E2, (bi.w + bh.w) * LOG2E2};
  }

  // B-frags: emb row v (f32 -> f16, unscaled -- scale lives in Wi/bias)
  const float* er = emb + (long)v * 64;
  float4 a0 = *(const float4*)(er + 8 * q);
  float4 a1 = *(const float4*)(er + 8 * q + 4);
  float4 a2 = *(const float4*)(er + 32 + 8 * q);
  float4 a3 = *(const float4*)(er + 32 + 8 * q + 4);
  f16x8 e0 = (f16x8){(f16)a0.x, (f16)a0.y, (f16)a0.z, (f16)a0.w,
                     (f16)a1.x, (f16)a1.y, (f16)a1.z, (f16)a1.w};
  f16x8 e1 = (f16x8){(f16)a2.x, (f16)a2.y, (f16)a2.z, (f16)a2.w,
                     (f16)a3.x, (f16)a3.y, (f16)a3.z, (f16)a3.w};

  // D[f][r] -> feat 16f+4q+r of row v(n)  (D layout: row=4q+r, col=n)
  f32x4 D[4];
  #pragma unroll
  for (int f = 0; f < 4; ++f) {
    D[f] = MFMA_K32(Wi[f][0], e0, bias[f]);
    D[f] = MFMA_K32(Wi[f][1], e1, D[f]);
  }
  if (ok) {
    f16* orow = embP + (long)v * 64 + 4 * q;
    #pragma unroll
    for (int f = 0; f < 4; ++f) {
      f16x4 o = (f16x4){(f16)D[f][0], (f16)D[f][1], (f16)D[f][2], (f16)D[f][3]};
      *(f16x4*)(orow + 16 * f) = o;
    }
  }
}

// ---- Kernel 1: gather + tanh-RNN scan. ONE wave per 16-row chain
// (256 blocks x 64 thr = 1 wave/CU). No LDS, no barriers: r3-validated
// register-resident recurrence via swapped product D = W*h^T with a
// permuted K ordering. This round uses the INTERLEAVED permutation
//   kappa(c; k) = 16*(2c + (k&1)) + 4*(k>>3) + ((k&7)>>1)
// so that B-chunk c's fragment VGPR p = {T_{2c}[p], T_{2c+1}[p]} -- the
// exact {lo,hi} pair the tanh+cvt pack produces naturally (no lane moves).
// A-fragments are built to match with one shufflevector at init.
// Input projection is pre-folded into embP (f16), so the gather directly
// initializes the accumulator; 4-deep rotating register prefetch covers
// ~900-cyc HBM latency. Per step: 4 b64 loads + 16 cvt + 8 MFMA + 16 tanh.
__global__ __launch_bounds__(64, 1) void rnn_scan_kernel(
    const int* __restrict__ xx, const f16* __restrict__ embP,
    const f16* __restrict__ whh,
    float* __restrict__ hT /* [HID][BATCH] */, float* __restrict__ bn_acc)
{
  const int L = threadIdx.x;       // 0..63
  const int n = L & 15;            // batch col within tile / W row within tile
  const int q = L >> 4;            // k-group
  const int R0 = blockIdx.x << 4;  // first batch row of this chain

  // A-frags, interleaved permutation: Wp[f][c] elems =
  // {lo0,hi0,lo1,hi1,lo2,hi2,lo3,hi3} with lo_e = Whh[16f+n][32c+4q+e],
  // hi_e = Whh[16f+n][32c+16+4q+e] (whh pre-scaled by LOG2E2).
  f16x8 Wp[4][2];
  #pragma unroll
  for (int f = 0; f < 4; ++f) {
    const f16* wr = whh + (16 * f + n) * 64;
    #pragma unroll
    for (int c = 0; c < 2; ++c) {
      f16x4 lo = *(const f16x4*)(wr + 32 * c + 4 * q);
      f16x4 hi = *(const f16x4*)(wr + 32 * c + 16 + 4 * q);
      Wp[f][c] = __builtin_shufflevector(lo, hi, 0, 4, 1, 5, 2, 6, 3, 7);
    }
  }

  // h state as next-step B-fragments (interleaved): hB01 = tiles {0,1},
  // hB23 = tiles {2,3}. h0 = 0.
  f16x8 hB01 = {0, 0, 0, 0, 0, 0, 0, 0};
  f16x8 hB23 = {0, 0, 0, 0, 0, 0, 0, 0};

  // idx stream: int4 = 4 steps; K1 holds steps 4(t+1)..4(t+1)+3.
  const int4* x4 = (const int4*)(xx + (R0 + n) * SEQ);
  int4 K1 = x4[1];

  // embP gather: lane (q,n) needs embP[id][16f+4q .. +3] for f=0..3
  // (4x b64 loads at imm offsets 0/32/64/96 B off one per-lane base).
  // 4-slot rotating register prefetch, distance 4 steps.
  const f16* ebase = embP + 4 * q;
  f16x4 g[4][4];                   // [slot][f-tile]
  {
    int4 K0 = x4[0];
    const int id0[4] = {K0.x, K0.y, K0.z, K0.w};
    #pragma unroll
    for (int u = 0; u < 4; ++u) {
      const f16* eb = ebase + (long)id0[u] * 64;
      #pragma unroll
      for (int f = 0; f < 4; ++f) g[u][f] = *(const f16x4*)(eb + 16 * f);
    }
  }

  for (int t = 0; t < SEQ / 4; ++t) {
    int4 K2 = x4[(t + 2 < SEQ / 4) ? t + 2 : SEQ / 4 - 1];  // clamped; dup loads harmless
    const int nid[4] = {K1.x, K1.y, K1.z, K1.w};            // idx for steps 4t+4+u
    const bool lastt = (t == SEQ / 4 - 1);

    #pragma unroll
    for (int u = 0; u < 4; ++u) {
      // D init = gathered input projection (bias & scale pre-folded).
      f32x4 D0 = (f32x4){(float)g[u][0][0], (float)g[u][0][1],
                         (float)g[u][0][2], (float)g[u][0][3]};
      f32x4 D1 = (f32x4){(float)g[u][1][0], (float)g[u][1][1],
                         (float)g[u][1][2], (float)g[u][1][3]};
      f32x4 D2 = (f32x4){(float)g[u][2][0], (float)g[u][2][1],
                         (float)g[u][2][2], (float)g[u][2][3]};
      f32x4 D3 = (f32x4){(float)g[u][3][0], (float)g[u][3][1],
                         (float)g[u][3][2], (float)g[u][3][3]};

      // recurrence chunk 0 (tiles {0,1} feats), then refill, then chunk 1.
      D0 = MFMA_K32(Wp[0][0], hB01, D0);
      D1 = MFMA_K32(Wp[1][0], hB01, D1);
      D2 = MFMA_K32(Wp[2][0], hB01, D2);
      D3 = MFMA_K32(Wp[3][0], hB01, D3);

      // refill slot u with step s+4 (stays in flight across 4 steps)
      {
        const f16* eb = ebase + (long)nid[u] * 64;
        #pragma unroll
        for (int f = 0; f < 4; ++f) g[u][f] = *(const f16x4*)(eb + 16 * f);
      }

      D0 = MFMA_K32(Wp[0][1], hB23, D0);
      D1 = MFMA_K32(Wp[1][1], hB23, D1);
      D2 = MFMA_K32(Wp[2][1], hB23, D2);
      D3 = MFMA_K32(Wp[3][1], hB23, D3);

      // tanh(v) = 1 - 2/(1 + 2^(2log2e*v)); exact saturation at +-1.
      // Pack: hB01 pair p = {t0[p], t1[p]}, hB23 pair p = {t2[p], t3[p]}
      // (interleaved kappa makes this the natural cvt lo/hi layout).
      float th[4][4];
      #pragma unroll
      for (int r = 0; r < 4; ++r) {
        float x0 = __builtin_amdgcn_exp2f(D0[r]);
        float x1 = __builtin_amdgcn_exp2f(D1[r]);
        float x2 = __builtin_amdgcn_exp2f(D2[r]);
        float x3 = __builtin_amdgcn_exp2f(D3[r]);
        th[0][r] = fmaf(-2.0f, __builtin_amdgcn_rcpf(x0 + 1.0f), 1.0f);
        th[1][r] = fmaf(-2.0f, __builtin_amdgcn_rcpf(x1 + 1.0f), 1.0f);
        th[2][r] = fmaf(-2.0f, __builtin_amdgcn_rcpf(x2 + 1.0f), 1.0f);
        th[3][r] = fmaf(-2.0f, __builtin_amdgcn_rcpf(x3 + 1.0f), 1.0f);
        hB01[2 * r]     = (f16)th[0][r];
        hB01[2 * r + 1] = (f16)th[1][r];
        hB23[2 * r]     = (f16)th[2][r];
        hB23[2 * r + 1] = (f16)th[3][r];
      }

      if (lastt && u == 3) {   // epilogue: h_n out + BN partial sums
        #pragma unroll
        for (int f = 0; f < 4; ++f) {
          #pragma unroll
          for (int r = 0; r < 4; ++r) {
            float v = th[f][r];
            const int feat = 16 * f + 4 * q + r;
            hT[feat * BATCH + R0 + n] = v;     // coalesced over n
            float s1 = v, s2 = v * v;
            s1 += __shfl_xor(s1, 1, 64);  s2 += __shfl_xor(s2, 1, 64);
            s1 += __shfl_xor(s1, 2, 64);  s2 += __shfl_xor(s2, 2, 64);
            s1 += __shfl_xor(s1, 4, 64);  s2 += __shfl_xor(s2, 4, 64);
            s1 += __shfl_xor(s1, 8, 64);  s2 += __shfl_xor(s2, 8, 64);
            if (n == 0) {
              atomicAdd(bn_acc + feat, s1);
              atomicAdd(bn_acc + 64 + feat, s2);
            }
          }
        }
      }
    }
    K1 = K2;
  }
}

// ---- Kernel 2: BN fold (from accumulated sums) + logits GEMV. fp32 out.
__global__ __launch_bounds__(256) void head_kernel(
    const float* __restrict__ hT, const float* __restrict__ bn_acc,
    const float* __restrict__ gamma, const float* __restrict__ beta,
    const float* __restrict__ Wfc, const float* __restrict__ bfc,
    float* __restrict__ out)
{
  __shared__ float sc[64], sh[64];
  const int tid = threadIdx.x;
  if (tid < 64) {
    float mean = bn_acc[tid] * (1.0f / BATCH);
    float var  = bn_acc[64 + tid] * (1.0f / BATCH) - mean * mean;  // biased
    float inv  = rsqrtf(var + 1e-5f);
    float s    = gamma[tid] * inv;
    sc[tid] = s;
    sh[tid] = beta[tid] - mean * s;
  }
  __syncthreads();
  const int b = blockIdx.x * 256 + tid;
  float acc[5];
  #pragma unroll
  for (int c = 0; c < 5; ++c) acc[c] = bfc[c];
  for (int j = 0; j < HID; ++j) {
    float hv  = hT[j * BATCH + b];                 // coalesced across lanes
    float hat = fmaf(hv, sc[j], sh[j]);
    #pragma unroll
    for (int c = 0; c < 5; ++c) acc[c] = fmaf(hat, Wfc[c * 64 + j], acc[c]);
  }
  #pragma unroll
  for (int c = 0; c < 5; ++c) out[b * 5 + c] = acc[c];
}

extern "C" void kernel_launch(void* const* d_in, const int* in_sizes, int n_in,
                              void* d_out, int out_size, void* d_ws, size_t ws_size,
                              hipStream_t stream)
{
  const int*   x     = (const int*)d_in[0];
  const float* emb   = (const float*)d_in[1];
  const float* W_ih  = (const float*)d_in[2];
  const float* W_hh  = (const float*)d_in[3];
  const float* b_ih  = (const float*)d_in[4];
  const float* b_hh  = (const float*)d_in[5];
  const float* gamma = (const float*)d_in[6];
  const float* beta  = (const float*)d_in[7];
  const float* W_fc  = (const float*)d_in[8];
  const float* b_fc  = (const float*)d_in[9];

  char* ws = (char*)d_ws;
  float* hT     = (float*)ws;                 // [64][4096] fp32, 1 MB
  float* bn_acc = (float*)(ws + 1048576);     // [2][64] fp32 atomics
  f16*   embP   = (f16*)(ws + 1049088);       // [50257][64] f16 projected, 6.43 MB
  f16*   whh_f  = (f16*)(ws + 7481984);       // [64][64] f16 (pre-scaled)

  prep_kernel<<<dim3(NBLK_GEMM + 1), dim3(256), 0, stream>>>(
      emb, W_ih, W_hh, b_ih, b_hh, embP, whh_f, bn_acc);
  rnn_scan_kernel<<<dim3(BATCH / 16), dim3(64), 0, stream>>>(
      x, embP, whh_f, hT, bn_acc);
  head_kernel<<<dim3(BATCH / 256), dim3(256), 0, stream>>>(
      hT, bn_acc, gamma, beta, W_fc, b_fc, (float*)d_out);
}

// Round 6
// 265.902 us; speedup vs baseline: 1.3393x; 1.1182x over previous
//
#include <hip/hip_runtime.h>

typedef _Float16 f16;
typedef __attribute__((ext_vector_type(4))) _Float16 f16x4;
typedef __attribute__((ext_vector_type(8))) _Float16 f16x8;
typedef __attribute__((ext_vector_type(4))) float f32x4;

constexpr int BATCH  = 4096;
constexpr int SEQ    = 512;
constexpr int HID    = 64;
constexpr int VOCAB  = 50257;
constexpr int NBLK_GEMM = 786;   // ceil(ceil(VOCAB/16)/4) GEMM blocks in prep
constexpr float LOG2E2 = 2.8853900817779268f;   // 2*log2(e), folded into embP/Whh

// Only the gfx950-verified K32 f16 shape is used.
#define MFMA_K32(a, b, c) __builtin_amdgcn_mfma_f32_16x16x32_f16(a, b, c, 0, 0, 0)

// ---- Prep (r5-proven): embP[v][f] = f16(LOG2E2*(bih+bhh)[f] + emb[v].Wih[f])
// as an MFMA GEMM; tail block converts Whh (pre-scaled) + zeroes BN acc.
__global__ __launch_bounds__(256) void prep_kernel(
    const float* __restrict__ emb, const float* __restrict__ Wih,
    const float* __restrict__ Whh, const float* __restrict__ bih,
    const float* __restrict__ bhh,
    f16* __restrict__ embP, f16* __restrict__ whh_f, float* __restrict__ bn_acc)
{
  const int bid = blockIdx.x;
  const int tid = threadIdx.x;
  if (bid == NBLK_GEMM) {        // tail: weight conversion + BN acc zero
    #pragma unroll
    for (int k = 0; k < 16; ++k) {
      const int i = tid * 16 + k;          // 256*16 = 4096 = HID*HID
      whh_f[i] = (f16)(Whh[i] * LOG2E2);
    }
    if (tid < 128) bn_acc[tid] = 0.f;      // ws is poisoned 0xAA every call
    return;
  }
  const int w = tid >> 6;          // wave -> one 16-row group
  const int L = tid & 63;
  const int n = L & 15;
  const int q = L >> 4;
  const int R0 = (bid * 4 + w) * 16;
  int v = R0 + n;
  const bool ok = v < VOCAB;
  if (!ok) v = VOCAB - 1;          // clamp loads; store guarded

  f16x8 Wi[4][2];
  f32x4 bias[4];
  #pragma unroll
  for (int f = 0; f < 4; ++f) {
    const float* wr = Wih + (16 * f + n) * 64;
    #pragma unroll
    for (int h = 0; h < 2; ++h) {
      float4 w0 = *(const float4*)(wr + 32 * h + 8 * q);
      float4 w1 = *(const float4*)(wr + 32 * h + 8 * q + 4);
      Wi[f][h] = (f16x8){
        (f16)(w0.x * LOG2E2), (f16)(w0.y * LOG2E2),
        (f16)(w0.z * LOG2E2), (f16)(w0.w * LOG2E2),
        (f16)(w1.x * LOG2E2), (f16)(w1.y * LOG2E2),
        (f16)(w1.z * LOG2E2), (f16)(w1.w * LOG2E2)};
    }
    float4 bi = *(const float4*)(bih + 16 * f + 4 * q);
    float4 bh = *(const float4*)(bhh + 16 * f + 4 * q);
    bias[f] = (f32x4){(bi.x + bh.x) * LOG2E2, (bi.y + bh.y) * LOG2E2,
                      (bi.z + bh.z) * LOG2E2, (bi.w + bh.w) * LOG2E2};
  }

  const float* er = emb + (long)v * 64;
  float4 a0 = *(const float4*)(er + 8 * q);
  float4 a1 = *(const float4*)(er + 8 * q + 4);
  float4 a2 = *(const float4*)(er + 32 + 8 * q);
  float4 a3 = *(const float4*)(er + 32 + 8 * q + 4);
  f16x8 e0 = (f16x8){(f16)a0.x, (f16)a0.y, (f16)a0.z, (f16)a0.w,
                     (f16)a1.x, (f16)a1.y, (f16)a1.z, (f16)a1.w};
  f16x8 e1 = (f16x8){(f16)a2.x, (f16)a2.y, (f16)a2.z, (f16)a2.w,
                     (f16)a3.x, (f16)a3.y, (f16)a3.z, (f16)a3.w};

  f32x4 D[4];
  #pragma unroll
  for (int f = 0; f < 4; ++f) {
    D[f] = MFMA_K32(Wi[f][0], e0, bias[f]);
    D[f] = MFMA_K32(Wi[f][1], e1, D[f]);
  }
  if (ok) {
    f16* orow = embP + (long)v * 64 + 4 * q;
    #pragma unroll
    for (int f = 0; f < 4; ++f) {
      f16x4 o = (f16x4){(f16)D[f][0], (f16)D[f][1], (f16)D[f][2], (f16)D[f][3]};
      *(f16x4*)(orow + 16 * f) = o;
    }
  }
}

// ---- Kernel 1: gather + tanh-RNN scan. TWO waves per 16-row chain
// (256 blocks x 128 thr) -- the r4 structure (best scan, 168us) with:
//  * interleaved-kappa K permutation (r5-HW-validated): B-chunk c elem k =
//    h[16*(2c+(k&1)) + 4q + (k>>1)], so wave w's packed tanh output IS
//    chunk w's fragment and the peer chunk needs no rearrangement.
//  * batched reciprocal: one v_rcp per 4 tanh values (1/(abcd) recovery),
//    trans/step/wave 16 -> 10. Requires s<=16 clamp (product <= 2^64;
//    tanh at s=16 already rounds to 1.0 in f16; negative side exact).
//  * exchange schedule: ds_read first after barrier; cvts + own-chunk
//    MFMAs + prefetch refill cover the LDS latency.
// Input projection pre-folded into embP; 4-deep rotating register
// prefetch covers gather latency; lgkmcnt-only barrier keeps it in flight.
__global__ __launch_bounds__(128, 1) void rnn_scan_kernel(
    const int* __restrict__ xx, const f16* __restrict__ embP,
    const f16* __restrict__ whh,
    float* __restrict__ hT /* [HID][BATCH] */, float* __restrict__ bn_acc)
{
  __shared__ int4 xslot[2][2][64];   // [parity][wave][lane], 16B fragments, 4 KB
  const int tid = threadIdx.x;
  const int w = tid >> 6;          // wave id: owns f-tiles {2w, 2w+1} = chunk w
  const int L = tid & 63;
  const int n = L & 15;            // batch col within tile / W row within tile
  const int q = L >> 4;            // k-group
  const int R0 = blockIdx.x << 4;  // first batch row of this chain

  // A-frags, interleaved kappa: Wp[j][c] elems {lo0,hi0,lo1,hi1,...} with
  // lo_e = Whh[16(2w+j)+n][32c+4q+e], hi_e = Whh[...][32c+16+4q+e].
  f16x8 Wp[2][2];
  #pragma unroll
  for (int j = 0; j < 2; ++j) {
    const f16* wr = whh + (16 * (2 * w + j) + n) * 64;
    #pragma unroll
    for (int c = 0; c < 2; ++c) {
      f16x4 lo = *(const f16x4*)(wr + 32 * c + 4 * q);
      f16x4 hi = *(const f16x4*)(wr + 32 * c + 16 + 4 * q);
      Wp[j][c] = __builtin_shufflevector(lo, hi, 0, 4, 1, 5, 2, 6, 3, 7);
    }
  }

  // Own h fragment (B-chunk w, interleaved) = 0; publish into parity-0 slot.
  f16x8 hOwn = {0, 0, 0, 0, 0, 0, 0, 0};
  xslot[0][w][L] = int4{0, 0, 0, 0};

  // idx stream: int4 = 4 steps; K1 holds steps 4(t+1)..4(t+1)+3.
  const int4* x4 = (const int4*)(xx + (R0 + n) * SEQ);
  int4 K1 = x4[1];

  // embP gather: lane (q,n) of wave w needs feats 16(2w+j)+4q..+3, j=0,1:
  // two b64 loads at imm offsets 0/+32B off one per-lane base.
  const f16* ebase = embP + 32 * w + 4 * q;
  f16x4 g0[4], g1[4];              // [slot] x {tile 2w, tile 2w+1}
  {
    int4 K0 = x4[0];
    const int id0[4] = {K0.x, K0.y, K0.z, K0.w};
    #pragma unroll
    for (int u = 0; u < 4; ++u) {
      const f16* eb = ebase + (long)id0[u] * 64;
      g0[u] = *(const f16x4*)(eb);
      g1[u] = *(const f16x4*)(eb + 16);
    }
  }

  // LDS-only barrier (h0 publish visible); vmcnt untouched -> prefetch lives.
  asm volatile("s_waitcnt lgkmcnt(0)\n\ts_barrier" ::: "memory");

  for (int t = 0; t < SEQ / 4; ++t) {
    int4 K2 = x4[(t + 2 < SEQ / 4) ? t + 2 : SEQ / 4 - 1];  // clamped; dup loads harmless
    const int nid[4] = {K1.x, K1.y, K1.z, K1.w};            // idx for steps 4t+4+u
    const bool lastt = (t == SEQ / 4 - 1);

    #pragma unroll
    for (int u = 0; u < 4; ++u) {
      const int p = u & 1;                       // step parity
      // Peer chunk for THIS step: read issued immediately after the barrier;
      // first use is after cvts + own-chunk MFMAs + refill.
      int4 oraw = xslot[p][w ^ 1][L];

      // D init = gathered input projection (bias & scale pre-folded).
      f32x4 D0 = (f32x4){(float)g0[u][0], (float)g0[u][1],
                         (float)g0[u][2], (float)g0[u][3]};
      f32x4 D1 = (f32x4){(float)g1[u][0], (float)g1[u][1],
                         (float)g1[u][2], (float)g1[u][3]};

      // Own-chunk MFMAs (chunk w): B-fragment is register-resident hOwn.
      D0 = MFMA_K32(Wp[0][w], hOwn, D0);
      D1 = MFMA_K32(Wp[1][w], hOwn, D1);

      // Refill slot u with step s+4 (stays in flight across 4 barriers).
      {
        const f16* eb = ebase + (long)nid[u] * 64;
        g0[u] = *(const f16x4*)(eb);
        g1[u] = *(const f16x4*)(eb + 16);
      }

      // Peer-chunk MFMAs.
      union { int4 i; f16x8 h; } cv; cv.i = oraw;
      D0 = MFMA_K32(Wp[0][w ^ 1], cv.h, D0);
      D1 = MFMA_K32(Wp[1][w ^ 1], cv.h, D1);

      // tanh(v) = 1 - 2/(1 + 2^s), s = 2log2e*v (pre-scaled).
      // Batched rcp: A_r = 1 + 2^min(s,16); one rcp per 4 values.
      float A0[4], A1[4];
      #pragma unroll
      for (int r = 0; r < 4; ++r) {
        A0[r] = __builtin_amdgcn_exp2f(fminf(D0[r], 16.0f)) + 1.0f;
        A1[r] = __builtin_amdgcn_exp2f(fminf(D1[r], 16.0f)) + 1.0f;
      }
      float th0[4], th1[4];
      {
        float t1 = A0[0] * A0[1], t2 = t1 * A0[2], t3 = t2 * A0[3];
        float rr = __builtin_amdgcn_rcpf(t3);
        float i3 = rr * t2;           // 1/A0[3]
        float s3 = rr * A0[3];        // 1/(A0[0]A0[1]A0[2])
        float i2 = s3 * t1;           // 1/A0[2]
        float s2 = s3 * A0[2];        // 1/(A0[0]A0[1])
        th0[0] = fmaf(-2.0f, s2 * A0[1], 1.0f);
        th0[1] = fmaf(-2.0f, s2 * A0[0], 1.0f);
        th0[2] = fmaf(-2.0f, i2, 1.0f);
        th0[3] = fmaf(-2.0f, i3, 1.0f);
      }
      {
        float t1 = A1[0] * A1[1], t2 = t1 * A1[2], t3 = t2 * A1[3];
        float rr = __builtin_amdgcn_rcpf(t3);
        float i3 = rr * t2;
        float s3 = rr * A1[3];
        float i2 = s3 * t1;
        float s2 = s3 * A1[2];
        th1[0] = fmaf(-2.0f, s2 * A1[1], 1.0f);
        th1[1] = fmaf(-2.0f, s2 * A1[0], 1.0f);
        th1[2] = fmaf(-2.0f, i2, 1.0f);
        th1[3] = fmaf(-2.0f, i3, 1.0f);
      }
      // Interleaved pack: hOwn pair r = {tile 2w [r], tile 2w+1 [r]} --
      // exactly chunk w's B-fragment for the next step.
      #pragma unroll
      for (int r = 0; r < 4; ++r) {
        hOwn[2 * r]     = (f16)th0[r];
        hOwn[2 * r + 1] = (f16)th1[r];
      }

      // Publish own new h for step s+1 into the other parity slot.
      union { f16x8 h; int4 i; } cw; cw.h = hOwn;
      xslot[p ^ 1][w][L] = cw.i;

      if (lastt && u == 3) {   // epilogue: h_n out + BN partial sums
        #pragma unroll
        for (int j = 0; j < 2; ++j) {
          #pragma unroll
          for (int r = 0; r < 4; ++r) {
            float v = j ? th1[r] : th0[r];
            const int feat = 16 * (2 * w + j) + 4 * q + r;
            hT[feat * BATCH + R0 + n] = v;     // coalesced over n
            float s1 = v, s2 = v * v;
            s1 += __shfl_xor(s1, 1, 64);  s2 += __shfl_xor(s2, 1, 64);
            s1 += __shfl_xor(s1, 2, 64);  s2 += __shfl_xor(s2, 2, 64);
            s1 += __shfl_xor(s1, 4, 64);  s2 += __shfl_xor(s2, 4, 64);
            s1 += __shfl_xor(s1, 8, 64);  s2 += __shfl_xor(s2, 8, 64);
            if (n == 0) {
              atomicAdd(bn_acc + feat, s1);
              atomicAdd(bn_acc + 64 + feat, s2);
            }
          }
        }
      }

      // LDS-only barrier: ds ops drained (lgkmcnt), vmcnt untouched.
      asm volatile("s_waitcnt lgkmcnt(0)\n\ts_barrier" ::: "memory");
    }
    K1 = K2;
  }
}

// ---- Kernel 2: BN fold (from accumulated sums) + logits GEMV. fp32 out.
__global__ __launch_bounds__(256) void head_kernel(
    const float* __restrict__ hT, const float* __restrict__ bn_acc,
    const float* __restrict__ gamma, const float* __restrict__ beta,
    const float* __restrict__ Wfc, const float* __restrict__ bfc,
    float* __restrict__ out)
{
  __shared__ float sc[64], sh[64];
  const int tid = threadIdx.x;
  if (tid < 64) {
    float mean = bn_acc[tid] * (1.0f / BATCH);
    float var  = bn_acc[64 + tid] * (1.0f / BATCH) - mean * mean;  // biased
    float inv  = rsqrtf(var + 1e-5f);
    float s    = gamma[tid] * inv;
    sc[tid] = s;
    sh[tid] = beta[tid] - mean * s;
  }
  __syncthreads();
  const int b = blockIdx.x * 256 + tid;
  float acc[5];
  #pragma unroll
  for (int c = 0; c < 5; ++c) acc[c] = bfc[c];
  for (int j = 0; j < HID; ++j) {
    float hv  = hT[j * BATCH + b];                 // coalesced across lanes
    float hat = fmaf(hv, sc[j], sh[j]);
    #pragma unroll
    for (int c = 0; c < 5; ++c) acc[c] = fmaf(hat, Wfc[c * 64 + j], acc[c]);
  }
  #pragma unroll
  for (int c = 0; c < 5; ++c) out[b * 5 + c] = acc[c];
}

extern "C" void kernel_launch(void* const* d_in, const int* in_sizes, int n_in,
                              void* d_out, int out_size, void* d_ws, size_t ws_size,
                              hipStream_t stream)
{
  const int*   x     = (const int*)d_in[0];
  const float* emb   = (const float*)d_in[1];
  const float* W_ih  = (const float*)d_in[2];
  const float* W_hh  = (const float*)d_in[3];
  const float* b_ih  = (const float*)d_in[4];
  const float* b_hh  = (const float*)d_in[5];
  const float* gamma = (const float*)d_in[6];
  const float* beta  = (const float*)d_in[7];
  const float* W_fc  = (const float*)d_in[8];
  const float* b_fc  = (const float*)d_in[9];

  char* ws = (char*)d_ws;
  float* hT     = (float*)ws;                 // [64][4096] fp32, 1 MB
  float* bn_acc = (float*)(ws + 1048576);     // [2][64] fp32 atomics
  f16*   embP   = (f16*)(ws + 1049088);       // [50257][64] f16 projected, 6.43 MB
  f16*   whh_f  = (f16*)(ws + 7481984);       // [64][64] f16 (pre-scaled)

  prep_kernel<<<dim3(NBLK_GEMM + 1), dim3(256), 0, stream>>>(
      emb, W_ih, W_hh, b_ih, b_hh, embP, whh_f, bn_acc);
  rnn_scan_kernel<<<dim3(BATCH / 16), dim3(128), 0, stream>>>(
      x, embP, whh_f, hT, bn_acc);
  head_kernel<<<dim3(BATCH / 256), dim3(256), 0, stream>>>(
      hT, bn_acc, gamma, beta, W_fc, b_fc, (float*)d_out);
}